// Round 4
// baseline (655.291 us; speedup 1.0000x reference)
//
#include <hip/hip_runtime.h>
#include <math.h>

#define B 8192
#define FA 848
#define FB 600
#define FC 264
#define ND 13
#define F 1725
#define KP1 1728   // F padded to multiple of 32 (also fp32-h row stride)
#define N1 1024
#define N2 512
#define N3 256
#define EPS 1e-5f
#define HALF1 864  // KP1/2

typedef __attribute__((ext_vector_type(4))) float f32x4;
typedef __attribute__((ext_vector_type(8))) short bf16x8;
typedef unsigned short u16;
typedef unsigned int u32;

__device__ __forceinline__ u16 f2bf(float x) {
  u32 b = __builtin_bit_cast(u32, x);
  u32 r = (b + 0x7fffu + ((b >> 16) & 1u)) >> 16;
  return (u16)r;
}
__device__ __forceinline__ float bf2f(u16 h) {
  return __builtin_bit_cast(float, (u32)h << 16);
}

// ============ K1: gather + concat + column stats (fused) ============
// grid (2, 256): blockIdx.x = column half [half*864, half*864+864),
// blockIdx.y = 32-row chunk. Writes h fp32 (stride KP1, pad zeroed),
// atomically accumulates per-column sum/sumsq into sums[0..F-1]/sums[F..2F-1].
__global__ __launch_bounds__(256) void gather_stats_kernel(
    const int* __restrict__ sparse, const float* __restrict__ dense,
    const float* __restrict__ ea, const float* __restrict__ eb,
    const float* __restrict__ ec, float* __restrict__ h,
    float* __restrict__ sums) {
  int half = blockIdx.x;
  int r0 = blockIdx.y * 32;
  int tid = threadIdx.x;
  float s[4] = {0.f, 0.f, 0.f, 0.f}, ss[4] = {0.f, 0.f, 0.f, 0.f};
  for (int rr = 0; rr < 32; ++rr) {
    int r = r0 + rr;
    const int* sp = sparse + r * 26;
    float* hr = h + (size_t)r * KP1;
#pragma unroll
    for (int e = 0; e < 4; ++e) {
      int off = tid + e * 256;
      if (off >= HALF1) continue;
      int j = half * HALF1 + off;
      float v = 0.f;
      if (j < FA) {
        int t = j / 106, c = j - t * 106;
        v = ea[(size_t)t * 10600000 + (size_t)sp[t] * 106 + c];
      } else if (j < FA + FB) {
        int jj = j - FA; int t = jj / 60, c = jj - t * 60;
        v = eb[(size_t)t * 600000 + (size_t)sp[8 + t] * 60 + c];
      } else if (j < FA + FB + FC) {
        int jj = j - FA - FB; int t = jj / 33, c = jj - t * 33;
        v = ec[(size_t)t * 33000 + (size_t)sp[18 + t] * 33 + c];
      } else if (j < F) {
        v = dense[r * ND + (j - (FA + FB + FC))];
      }
      hr[j] = v;
      s[e] += v;
      ss[e] += v * v;
    }
  }
#pragma unroll
  for (int e = 0; e < 4; ++e) {
    int off = tid + e * 256;
    if (off >= HALF1) continue;
    int j = half * HALF1 + off;
    if (j < F) {
      atomicAdd(&sums[j], s[e]);
      atomicAdd(&sums[F + j], ss[e]);
    }
  }
}

// ============ K2: weight transpose/cast ×3 + cross-constant prep (flat grid) ====
__device__ void convw_tile(const float* __restrict__ W, int K, int N, int Kp,
                           u16* __restrict__ Wt, int nt, int kt, int tid) {
  __shared__ float t[32][33];
  int tx = tid & 31, ty = tid >> 5;  // 32 x 8
  int n0 = nt * 32, k0 = kt * 32;
#pragma unroll
  for (int i = 0; i < 4; ++i) {
    int k = k0 + ty + i * 8;
    t[ty + i * 8][tx] = (k < K) ? W[(size_t)k * N + n0 + tx] : 0.f;
  }
  __syncthreads();
#pragma unroll
  for (int i = 0; i < 4; ++i) {
    int n = n0 + ty + i * 8;
    Wt[(size_t)n * Kp + k0 + tx] = f2bf(t[tx][ty + i * 8]);
  }
}

// consts[0..2] = d_1..d_3 (d_i = (sum_{j<i} cb_j) @ cw_i), consts[3] = e =
// (cb0+cb1+cb2+cb3) @ Wout[0:F]
__device__ void prep_body(const float* __restrict__ cw,
                          const float* __restrict__ cb,
                          const float* __restrict__ wout,
                          float* __restrict__ consts, int tid) {
  float a0 = 0.f, a1 = 0.f, a2 = 0.f, a3 = 0.f;
  for (int j = tid; j < F; j += 256) {
    float c1 = cb[j];
    float c2 = c1 + cb[F + j];
    float c3 = c2 + cb[2 * F + j];
    float c4 = c3 + cb[3 * F + j];
    a0 += c1 * cw[F + j];
    a1 += c2 * cw[2 * F + j];
    a2 += c3 * cw[3 * F + j];
    a3 += c4 * wout[j];
  }
  __shared__ float red[4][4];
  int lane = tid & 63, wid = tid >> 6;
  float acc[4] = {a0, a1, a2, a3};
#pragma unroll
  for (int q = 0; q < 4; ++q) {
    float v = acc[q];
    for (int off = 32; off; off >>= 1) v += __shfl_down(v, off, 64);
    if (lane == 0) red[q][wid] = v;
  }
  __syncthreads();
  if (tid == 0) {
#pragma unroll
    for (int q = 0; q < 4; ++q)
      consts[q] = red[q][0] + red[q][1] + red[q][2] + red[q][3];
  }
}

#define T1 1728  // (N1/32)*(KP1/32) = 32*54
#define T2 512   // (N2/32)*(N1/32)  = 16*32
#define T3 128   // (N3/32)*(N2/32)  = 8*16
__global__ __launch_bounds__(256) void weights_prep_kernel(
    const float* __restrict__ W1, const float* __restrict__ W2,
    const float* __restrict__ W3, const float* __restrict__ cw,
    const float* __restrict__ cb, const float* __restrict__ wout,
    u16* __restrict__ W1t, u16* __restrict__ W2t, u16* __restrict__ W3t,
    float* __restrict__ consts) {
  int b = blockIdx.x, tid = threadIdx.x;
  if (b < T1) {
    convw_tile(W1, F, N1, KP1, W1t, b & 31, b >> 5, tid);
  } else if (b < T1 + T2) {
    int t = b - T1;
    convw_tile(W2, N1, N2, N1, W2t, t & 15, t >> 4, tid);
  } else if (b < T1 + T2 + T3) {
    int t = b - T1 - T2;
    convw_tile(W3, N2, N3, N2, W3t, t & 7, t >> 3, tid);
  } else {
    prep_body(cw, cb, wout, consts, tid);
  }
}

// ============ K3: BN(h) -> bf16 hbf + cross GEMV + recurrence (fused) ============
// grid 2048 blocks x 4 rows. Reads h fp32 + sums, writes hbf (BN'd, padded),
// computes cpart[r] via the collapsed cross recurrence (fp32 dots).
__global__ __launch_bounds__(256) void bn_gemv_kernel(
    const float* __restrict__ h, const float* __restrict__ sums,
    const float* __restrict__ cw, const float* __restrict__ wout,
    const float* __restrict__ consts, u16* __restrict__ hbf,
    float* __restrict__ cpart) {
  int tid = threadIdx.x;
  float m[4][2], inv[4][2], w[5][4][2];
#pragma unroll
  for (int e = 0; e < 4; ++e) {
    int jj = tid + e * 256;
#pragma unroll
    for (int hf = 0; hf < 2; ++hf) {
      int c = 2 * jj + hf;
      if (jj < HALF1 && c < F) {
        float sm = sums[c] * (1.f / B);
        float sq = sums[F + c] * (1.f / B);
        m[e][hf] = sm;
        inv[e][hf] = rsqrtf(sq - sm * sm + EPS);
        w[0][e][hf] = cw[c];
        w[1][e][hf] = cw[F + c];
        w[2][e][hf] = cw[2 * F + c];
        w[3][e][hf] = cw[3 * F + c];
        w[4][e][hf] = wout[c];
      } else {
        m[e][hf] = 0.f; inv[e][hf] = 0.f;
#pragma unroll
        for (int i = 0; i < 5; ++i) w[i][e][hf] = 0.f;
      }
    }
  }
  __shared__ float red[5][4];
  int lane = tid & 63, wid = tid >> 6;
  int r0 = blockIdx.x * 4;
  for (int rr = 0; rr < 4; ++rr) {
    int r = r0 + rr;
    const float* hr = h + (size_t)r * KP1;
    u32* br = (u32*)(hbf + (size_t)r * KP1);
    float p[5] = {0.f, 0.f, 0.f, 0.f, 0.f};
#pragma unroll
    for (int e = 0; e < 4; ++e) {
      int jj = tid + e * 256;
      if (jj >= HALF1) continue;
      float2 x = *(const float2*)(hr + 2 * jj);
      float y0 = (x.x - m[e][0]) * inv[e][0];
      float y1 = (x.y - m[e][1]) * inv[e][1];
      br[jj] = (u32)f2bf(y0) | ((u32)f2bf(y1) << 16);
#pragma unroll
      for (int i = 0; i < 5; ++i)
        p[i] += y0 * w[i][e][0] + y1 * w[i][e][1];
    }
#pragma unroll
    for (int i = 0; i < 5; ++i) {
      float v = p[i];
      for (int off = 32; off; off >>= 1) v += __shfl_down(v, off, 64);
      if (lane == 0) red[i][wid] = v;
    }
    __syncthreads();
    if (tid == 0) {
      float u[5];
#pragma unroll
      for (int i = 0; i < 5; ++i)
        u[i] = red[i][0] + red[i][1] + red[i][2] + red[i][3];
      float dd[4] = {0.f, consts[0], consts[1], consts[2]};
      float a = 1.f;
#pragma unroll
      for (int i = 0; i < 4; ++i) a += a * u[i] + dd[i];
      cpart[r] = a * u[4] + consts[3];
    }
    __syncthreads();
  }
}

// ============ K4/6/8: bf16 MFMA GEMM + fused column-stats epilogue ============
template <bool OUT_BF>
__global__ __launch_bounds__(256) void gemm_bf16_kernel(
    const u16* __restrict__ A, const u16* __restrict__ Bt,
    void* __restrict__ Cout, float* __restrict__ gsum, int N, int K) {
  __shared__ u16 As[128 * 32];
  __shared__ u16 Bs[128 * 32];
  int tid = threadIdx.x;
  int lane = tid & 63;
  int wave = tid >> 6;
  int row0 = blockIdx.y * 128, col0 = blockIdx.x * 128;
  int wm = (wave >> 1) * 64, wn = (wave & 1) * 64;
  int mrow = lane & 15;
  int kq = lane >> 4;

  f32x4 acc[4][4];
#pragma unroll
  for (int i = 0; i < 4; ++i)
#pragma unroll
    for (int j = 0; j < 4; ++j) acc[i][j] = (f32x4){0.f, 0.f, 0.f, 0.f};

  int kc = (tid & 3) * 8;
  const u16* Ag = A + (size_t)row0 * K;
  const u16* Bg = Bt + (size_t)col0 * K;

  for (int k0 = 0; k0 < K; k0 += 32) {
#pragma unroll
    for (int i = 0; i < 2; ++i) {
      int u = i * 256 + tid;
      int rr = u >> 2;
      __builtin_amdgcn_global_load_lds(
          (const __attribute__((address_space(1))) u32*)(Ag + (size_t)rr * K + k0 + kc),
          (__attribute__((address_space(3))) u32*)(As + u * 8), 16, 0, 0);
      __builtin_amdgcn_global_load_lds(
          (const __attribute__((address_space(1))) u32*)(Bg + (size_t)rr * K + k0 + kc),
          (__attribute__((address_space(3))) u32*)(Bs + u * 8), 16, 0, 0);
    }
    __syncthreads();
    bf16x8 af[4], bfr[4];
#pragma unroll
    for (int mi = 0; mi < 4; ++mi)
      af[mi] = *(const bf16x8*)(As + (wm + mi * 16 + mrow) * 32 + kq * 8);
#pragma unroll
    for (int ni = 0; ni < 4; ++ni)
      bfr[ni] = *(const bf16x8*)(Bs + (wn + ni * 16 + mrow) * 32 + kq * 8);
#pragma unroll
    for (int mi = 0; mi < 4; ++mi)
#pragma unroll
      for (int ni = 0; ni < 4; ++ni)
        acc[mi][ni] = __builtin_amdgcn_mfma_f32_16x16x32_bf16(
            af[mi], bfr[ni], acc[mi][ni], 0, 0, 0);
    __syncthreads();
  }

  float* sred = (float*)As;  // 256 floats: [0..127]=sum, [128..255]=sumsq
  sred[tid] = 0.f;
  __syncthreads();
#pragma unroll
  for (int ni = 0; ni < 4; ++ni) {
    int col_l = wn + ni * 16 + mrow;
    int col = col0 + col_l;
    float s = 0.f, ss = 0.f;
#pragma unroll
    for (int mi = 0; mi < 4; ++mi) {
#pragma unroll
      for (int reg = 0; reg < 4; ++reg) {
        int row = row0 + wm + mi * 16 + kq * 4 + reg;
        float v = acc[mi][ni][reg];
        if (OUT_BF) {
          u16 hb = f2bf(v);
          v = bf2f(hb);
          ((u16*)Cout)[(size_t)row * N + col] = hb;
        } else {
          ((float*)Cout)[(size_t)row * N + col] = v;
        }
        s += v;
        ss += v * v;
      }
    }
    s += __shfl_xor(s, 16, 64);  s += __shfl_xor(s, 32, 64);
    ss += __shfl_xor(ss, 16, 64); ss += __shfl_xor(ss, 32, 64);
    if (kq == 0) {
      atomicAdd(&sred[col_l], s);
      atomicAdd(&sred[128 + col_l], ss);
    }
  }
  __syncthreads();
  if (tid < 128) {
    atomicAdd(&gsum[col0 + tid], sred[tid]);
    atomicAdd(&gsum[N + col0 + tid], sred[128 + tid]);
  }
}

// ============ K5/7: BN + relu, bf16 -> bf16, m/inv inline from gsum ============
__global__ __launch_bounds__(256) void bn_relu_bb_kernel(
    const uint4* __restrict__ X, const float* __restrict__ gsum,
    uint4* __restrict__ out, int Cmask, int total8) {
  int i = blockIdx.x * 256 + threadIdx.x;
  if (i >= total8) return;
  uint4 v = X[i];
  int colb = (i << 3) & Cmask;
  int C = Cmask + 1;
  u32 wv[4] = {v.x, v.y, v.z, v.w};
  u32 o[4];
#pragma unroll
  for (int e = 0; e < 4; ++e) {
    int c0 = colb + e * 2, c1 = c0 + 1;
    float m0 = gsum[c0] * (1.f / B), q0 = gsum[C + c0] * (1.f / B);
    float m1 = gsum[c1] * (1.f / B), q1 = gsum[C + c1] * (1.f / B);
    float i0 = rsqrtf(q0 - m0 * m0 + EPS);
    float i1 = rsqrtf(q1 - m1 * m1 + EPS);
    float x0 = bf2f((u16)(wv[e] & 0xffffu));
    float x1 = bf2f((u16)(wv[e] >> 16));
    x0 = fmaxf((x0 - m0) * i0, 0.f);
    x1 = fmaxf((x1 - m1) * i1, 0.f);
    o[e] = (u32)f2bf(x0) | ((u32)f2bf(x1) << 16);
  }
  out[i] = make_uint4(o[0], o[1], o[2], o[3]);
}

// ============ K9: BN(z3)+relu+dot+sigmoid (fused final) ============
__global__ __launch_bounds__(256) void final_kernel(
    const float* __restrict__ cpart, const u16* __restrict__ z3,
    const float* __restrict__ gsum, const float* __restrict__ wout,
    float* __restrict__ out) {
  int r = blockIdx.x, c = threadIdx.x;
  float sm = gsum[c] * (1.f / B), sq = gsum[N3 + c] * (1.f / B);
  float inv = rsqrtf(sq - sm * sm + EPS);
  float x = bf2f(z3[(size_t)r * N3 + c]);
  float local = fmaxf((x - sm) * inv, 0.f) * wout[F + c];
  for (int off = 32; off; off >>= 1) local += __shfl_down(local, off, 64);
  __shared__ float red[4];
  int lane = c & 63, wid = c >> 6;
  if (lane == 0) red[wid] = local;
  __syncthreads();
  if (c == 0) {
    float s = cpart[r] + red[0] + red[1] + red[2] + red[3];
    out[r] = 1.0f / (1.0f + expf(-s));
  }
}

extern "C" void kernel_launch(void* const* d_in, const int* in_sizes, int n_in,
                              void* d_out, int out_size, void* d_ws,
                              size_t ws_size, hipStream_t stream) {
  const int* sparse = (const int*)d_in[0];
  const float* dense = (const float*)d_in[1];
  const float* ea = (const float*)d_in[2];
  const float* eb = (const float*)d_in[3];
  const float* ec = (const float*)d_in[4];
  const float* cw = (const float*)d_in[5];
  const float* cb = (const float*)d_in[6];
  const float* W1 = (const float*)d_in[7];
  const float* W2 = (const float*)d_in[9];
  const float* W3 = (const float*)d_in[11];
  const float* Wout = (const float*)d_in[13];
  float* out = (float*)d_out;

  float* ws = (float*)d_ws;
  size_t o = 0;
  float* h = ws + o;      o += (size_t)B * KP1;     // 56.6 MB fp32 (padded)
  float* cpart = ws + o;  o += B;
  float* stats = ws + o;  o += 7040;                // sums + gsum1/2/3 (one memset)
  float* sums = stats;
  float* gsum1 = stats + 2 * F;
  float* gsum2 = gsum1 + 2 * N1;
  float* gsum3 = gsum2 + 2 * N2;
  float* consts = ws + o; o += 8;
  u16* hbf = (u16*)(ws + o);  o += (size_t)B * KP1 / 2;
  u16* z1 = (u16*)(ws + o);   o += (size_t)B * N1 / 2;
  u16* z1n = (u16*)(ws + o);  o += (size_t)B * N1 / 2;
  u16* z2 = (u16*)(ws + o);   o += (size_t)B * N2 / 2;
  u16* z2n = (u16*)(ws + o);  o += (size_t)B * N2 / 2;
  u16* z3 = (u16*)(ws + o);   o += (size_t)B * N3 / 2;
  u16* W1t = (u16*)(ws + o);  o += (size_t)N1 * KP1 / 2;
  u16* W2t = (u16*)(ws + o);  o += (size_t)N2 * N1 / 2;
  u16* W3t = (u16*)(ws + o);  o += (size_t)N3 * N2 / 2;

  hipMemsetAsync(stats, 0, 7040 * sizeof(float), stream);

  weights_prep_kernel<<<T1 + T2 + T3 + 1, 256, 0, stream>>>(
      W1, W2, W3, cw, cb, Wout, W1t, W2t, W3t, consts);

  gather_stats_kernel<<<dim3(2, 256), 256, 0, stream>>>(
      sparse, dense, ea, eb, ec, h, sums);

  bn_gemv_kernel<<<B / 4, 256, 0, stream>>>(
      h, sums, cw, Wout, consts, hbf, cpart);

  gemm_bf16_kernel<true><<<dim3(N1 / 128, B / 128), 256, 0, stream>>>(
      hbf, W1t, (void*)z1, gsum1, N1, KP1);
  bn_relu_bb_kernel<<<(B * N1 / 8 + 255) / 256, 256, 0, stream>>>(
      (const uint4*)z1, gsum1, (uint4*)z1n, N1 - 1, B * N1 / 8);

  gemm_bf16_kernel<true><<<dim3(N2 / 128, B / 128), 256, 0, stream>>>(
      z1n, W2t, (void*)z2, gsum2, N2, N1);
  bn_relu_bb_kernel<<<(B * N2 / 8 + 255) / 256, 256, 0, stream>>>(
      (const uint4*)z2, gsum2, (uint4*)z2n, N2 - 1, B * N2 / 8);

  gemm_bf16_kernel<true><<<dim3(N3 / 128, B / 128), 256, 0, stream>>>(
      z2n, W3t, (void*)z3, gsum3, N3, N2);

  final_kernel<<<B, 256, 0, stream>>>(cpart, z3, gsum3, Wout, out);
}